// Round 1
// baseline (1947.669 us; speedup 1.0000x reference)
//
#include <hip/hip_runtime.h>

#define HID 30
#define TSTEPS 2048
#define BATCH 512
#define L2E 1.4426950408889634f

// Wave-per-batch persistent LSTM.
// lane = (k = lane&31, h = lane>>5). h=0 -> gates {i,f} of unit k; h=1 -> {g,o}.
// Weights held in VGPRs (launch_bounds(64,1) -> up to ~512 VGPRs, no spill).
__global__ __launch_bounds__(64, 1)
void lstm2_kernel(const float* __restrict__ x,
                  const float* __restrict__ w_ih1, const float* __restrict__ w_hh1,
                  const float* __restrict__ b_ih1, const float* __restrict__ b_hh1,
                  const float* __restrict__ w_ih2, const float* __restrict__ w_hh2,
                  const float* __restrict__ b_ih2, const float* __restrict__ b_hh2,
                  const float* __restrict__ w_fc,  const float* __restrict__ b_fc,
                  float* __restrict__ out)
{
    const int b    = blockIdx.x;
    const int lane = threadIdx.x;
    const int k    = lane & 31;
    const int h    = lane >> 5;
    const int kk   = (k < HID) ? k : (HID - 1);   // lanes 30,31 duplicate unit 29 (harmless)
    const int rowA = h * 60 + kk;        // h=0: i-row, h=1: g-row
    const int rowB = h * 60 + 30 + kk;   // h=0: f-row, h=1: o-row

    __shared__ __align__(16) float h1buf[64];
    __shared__ __align__(16) float h2buf[64];
    h1buf[lane] = 0.0f;
    h2buf[lane] = 0.0f;
    __syncthreads();

    // ---- load loop-invariant per-lane weights into registers (padded j to 32) ----
    float2 whh1[32], wih2[32], whh2[32];
#pragma unroll
    for (int j = 0; j < 32; ++j) {
        if (j < HID) {
            whh1[j] = make_float2(w_hh1[rowA * HID + j], w_hh1[rowB * HID + j]);
            wih2[j] = make_float2(w_ih2[rowA * HID + j], w_ih2[rowB * HID + j]);
            whh2[j] = make_float2(w_hh2[rowA * HID + j], w_hh2[rowB * HID + j]);
        } else {
            whh1[j] = make_float2(0.0f, 0.0f);
            wih2[j] = make_float2(0.0f, 0.0f);
            whh2[j] = make_float2(0.0f, 0.0f);
        }
    }
    const float2 wih1p = make_float2(w_ih1[rowA], w_ih1[rowB]);
    const float2 b1p   = make_float2(b_ih1[rowA] + b_hh1[rowA], b_ih1[rowB] + b_hh1[rowB]);
    const float2 b2p   = make_float2(b_ih2[rowA] + b_hh2[rowA], b_ih2[rowB] + b_hh2[rowB]);
    const float  wfck  = (k < HID) ? w_fc[k] : 0.0f;
    const float  bfc   = b_fc[0];

    // activation lane-constants: gate a is sigmoid (h=0) or tanh (h=1); gate b always sigmoid
    const float cA = h ? (-2.0f * L2E) : (-L2E); // exp2 scale for gate a
    const float cM = h ? 2.0f : 1.0f;            // post-scale   (tanh = 2*sig(2x)-1)
    const float cC = h ? -1.0f : 0.0f;

    float c1 = 0.0f, c2 = 0.0f;
    float xv = 0.0f;

    const float4* h1v = (const float4*)h1buf;
    const float4* h2v = (const float4*)h2buf;
    const float* xp   = x   + (size_t)b * TSTEPS;
    float*       outp = out + (size_t)b * TSTEPS;

    for (int t = 0; t <= TSTEPS; ++t) {
        // ---- broadcast-read h1(t-1) and h2(t-2) vectors from LDS ----
        float4 H1c[8], H2c[8];
#pragma unroll
        for (int c = 0; c < 8; ++c) { H1c[c] = h1v[c]; H2c[c] = h2v[c]; }

        if (t > 0) {
            // ================= layer 2, step t-1 =================
            float2 pre = b2p;
#pragma unroll
            for (int c = 0; c < 8; ++c) {
                const float* a1 = (const float*)&H1c[c];
                const float* a2 = (const float*)&H2c[c];
#pragma unroll
                for (int e = 0; e < 4; ++e) {
                    const int j = 4 * c + e;
                    pre.x = fmaf(wih2[j].x, a1[e], fmaf(whh2[j].x, a2[e], pre.x));
                    pre.y = fmaf(wih2[j].y, a1[e], fmaf(whh2[j].y, a2[e], pre.y));
                }
            }
            float ea = __builtin_amdgcn_exp2f(pre.x * cA);
            float ua = __builtin_amdgcn_rcpf(1.0f + ea);
            float ga = fmaf(ua, cM, cC);                      // h=0: i,  h=1: g
            float eb = __builtin_amdgcn_exp2f(pre.y * (-L2E));
            float gb = __builtin_amdgcn_rcpf(1.0f + eb);      // h=0: f,  h=1: o
            float ra = __shfl_xor(ga, 32);
            float rb = __shfl_xor(gb, 32);
            float gi = h ? ra : ga;
            float gf = h ? rb : gb;
            float gg = h ? ga : ra;
            float go = h ? gb : rb;
            c2 = fmaf(gf, c2, gi * gg);
            float ec = __builtin_amdgcn_exp2f(c2 * (-2.0f * L2E));
            float tc = fmaf(2.0f, __builtin_amdgcn_rcpf(1.0f + ec), -1.0f);
            float hh = go * tc;                                // h2(t-1), both halves
            h2buf[lane] = hh;
            // fc head: out[t-1] = w_fc . h2(t-1) + b_fc  (32-wide shuffle reduce)
            float s = wfck * hh;
#pragma unroll
            for (int m = 16; m >= 1; m >>= 1) s += __shfl_xor(s, m, 32);
            if (lane == 0) outp[t - 1] = s + bfc;
        }

        if (t < TSTEPS) {
            // ================= layer 1, step t =================
            if ((t & 63) == 0) xv = xp[t + lane];   // coalesced chunk of 64 timesteps
            float xt = __shfl(xv, t & 63);
            float2 pre;
            pre.x = fmaf(xt, wih1p.x, b1p.x);
            pre.y = fmaf(xt, wih1p.y, b1p.y);
#pragma unroll
            for (int c = 0; c < 8; ++c) {
                const float* a1 = (const float*)&H1c[c];   // h1(t-1), reused from phase A
#pragma unroll
                for (int e = 0; e < 4; ++e) {
                    const int j = 4 * c + e;
                    pre.x = fmaf(whh1[j].x, a1[e], pre.x);
                    pre.y = fmaf(whh1[j].y, a1[e], pre.y);
                }
            }
            float ea = __builtin_amdgcn_exp2f(pre.x * cA);
            float ua = __builtin_amdgcn_rcpf(1.0f + ea);
            float ga = fmaf(ua, cM, cC);
            float eb = __builtin_amdgcn_exp2f(pre.y * (-L2E));
            float gb = __builtin_amdgcn_rcpf(1.0f + eb);
            float ra = __shfl_xor(ga, 32);
            float rb = __shfl_xor(gb, 32);
            float gi = h ? ra : ga;
            float gf = h ? rb : gb;
            float gg = h ? ga : ra;
            float go = h ? gb : rb;
            c1 = fmaf(gf, c1, gi * gg);
            float ec = __builtin_amdgcn_exp2f(c1 * (-2.0f * L2E));
            float tc = fmaf(2.0f, __builtin_amdgcn_rcpf(1.0f + ec), -1.0f);
            float hh = go * tc;                                // h1(t)
            h1buf[lane] = hh;
        }
    }
}

extern "C" void kernel_launch(void* const* d_in, const int* in_sizes, int n_in,
                              void* d_out, int out_size, void* d_ws, size_t ws_size,
                              hipStream_t stream)
{
    const float* x     = (const float*)d_in[0];
    const float* w_ih1 = (const float*)d_in[1];
    const float* w_hh1 = (const float*)d_in[2];
    const float* b_ih1 = (const float*)d_in[3];
    const float* b_hh1 = (const float*)d_in[4];
    const float* w_ih2 = (const float*)d_in[5];
    const float* w_hh2 = (const float*)d_in[6];
    const float* b_ih2 = (const float*)d_in[7];
    const float* b_hh2 = (const float*)d_in[8];
    const float* w_fc  = (const float*)d_in[9];
    const float* b_fc  = (const float*)d_in[10];
    float* out = (float*)d_out;

    lstm2_kernel<<<BATCH, 64, 0, stream>>>(x, w_ih1, w_hh1, b_ih1, b_hh1,
                                           w_ih2, w_hh2, b_ih2, b_hh2,
                                           w_fc, b_fc, out);
}

// Round 3
// 1371.523 us; speedup vs baseline: 1.4201x; 1.4201x over previous
//
#include <hip/hip_runtime.h>

typedef float v2f __attribute__((ext_vector_type(2)));
typedef float v4f __attribute__((ext_vector_type(4)));

#define HID 30
#define TSTEPS 2048
#define BATCH 512
#define L2E 1.4426950408889634f

// acc(pair) += w(pair) * broadcast(src1.lo)  — VOP3P needs PAIR operands (R2 lesson).
__device__ __forceinline__ void pk_fma_lo(v2f& acc, v2f w, v2f hp) {
    asm("v_pk_fma_f32 %0, %1, %2, %0 op_sel:[0,0,0] op_sel_hi:[1,0,1]"
        : "+v"(acc) : "v"(w), "v"(hp));
}
// acc(pair) += w(pair) * broadcast(src1.hi)
__device__ __forceinline__ void pk_fma_hi(v2f& acc, v2f w, v2f hp) {
    asm("v_pk_fma_f32 %0, %1, %2, %0 op_sel:[0,1,0] op_sel_hi:[1,1,1]"
        : "+v"(acc) : "v"(w), "v"(hp));
}
// Opaque barrier: forbids rematerializing weight loads inside the t-loop.
__device__ __forceinline__ void pin2(v2f& v) { asm("" : "+v"(v)); }
__device__ __forceinline__ void pinf(float& v) { asm("" : "+v"(v)); }

__device__ __forceinline__ float fexp2(float x) { return __builtin_amdgcn_exp2f(x); }
__device__ __forceinline__ float frcp(float x)  { return __builtin_amdgcn_rcpf(x); }

// Wave-wide sum via DPP (VALU pipe; keeps the DS queue clear). Valid in lane 63.
__device__ __forceinline__ float dpp_reduce63(float x) {
    x += __int_as_float(__builtin_amdgcn_update_dpp(0, __float_as_int(x), 0x111, 0xf, 0xf, true));
    x += __int_as_float(__builtin_amdgcn_update_dpp(0, __float_as_int(x), 0x112, 0xf, 0xf, true));
    x += __int_as_float(__builtin_amdgcn_update_dpp(0, __float_as_int(x), 0x114, 0xf, 0xf, true));
    x += __int_as_float(__builtin_amdgcn_update_dpp(0, __float_as_int(x), 0x118, 0xf, 0xf, true));
    x += __int_as_float(__builtin_amdgcn_update_dpp(0, __float_as_int(x), 0x142, 0xf, 0xf, true));
    x += __int_as_float(__builtin_amdgcn_update_dpp(0, __float_as_int(x), 0x143, 0xf, 0xf, true));
    return x;
}

// Wave-per-batch persistent 2-layer LSTM.
// lane = (k = lane&31, h = lane>>5). Gate split {i,g} on h=0, {f,o} on h=1:
// one cross-half shuffle (the i*g product) per phase; c and h live in the h=1 half.
__global__ __launch_bounds__(64, 1)
void lstm2_kernel(const float* __restrict__ x,
                  const float* __restrict__ w_ih1, const float* __restrict__ w_hh1,
                  const float* __restrict__ b_ih1, const float* __restrict__ b_hh1,
                  const float* __restrict__ w_ih2, const float* __restrict__ w_hh2,
                  const float* __restrict__ b_ih2, const float* __restrict__ b_hh2,
                  const float* __restrict__ w_fc,  const float* __restrict__ b_fc,
                  float* __restrict__ out)
{
    const int b    = blockIdx.x;
    const int lane = threadIdx.x;
    const int k    = lane & 31;
    const int h    = lane >> 5;
    const int kk   = (k < HID) ? k : (HID - 1);   // lanes k=30,31 duplicate unit 29
    const int rowA = h * 30 + kk;        // h0: i-row,  h1: f-row
    const int rowB = 60 + h * 30 + kk;   // h0: g-row,  h1: o-row
    // h=1 writes the real h at [kk]; h=0 dumps its duplicate at [kk+32]
    const int wr_off = kk + (h ? 0 : 32);

    // h1 double-buffered by t-parity (L2 phase needs h1(t-1) after L1 wrote h1(t)).
    __shared__ __align__(16) float h1buf[128];
    __shared__ __align__(16) float h2buf[64];
    h1buf[lane]      = 0.0f;
    h1buf[lane + 64] = 0.0f;
    h2buf[lane]      = 0.0f;
    __syncthreads();

    // ---- loop-invariant per-lane packed (rowA,rowB) weights in VGPRs; j padded to 32 ----
    v2f whh1[32], wih2[32], whh2[32];
#pragma unroll
    for (int j = 0; j < 32; ++j) {
        if (j < HID) {
            whh1[j] = (v2f){w_hh1[rowA * HID + j], w_hh1[rowB * HID + j]};
            wih2[j] = (v2f){w_ih2[rowA * HID + j], w_ih2[rowB * HID + j]};
            whh2[j] = (v2f){w_hh2[rowA * HID + j], w_hh2[rowB * HID + j]};
        } else {
            whh1[j] = (v2f){0.0f, 0.0f};
            wih2[j] = (v2f){0.0f, 0.0f};
            whh2[j] = (v2f){0.0f, 0.0f};
        }
    }
#pragma unroll
    for (int j = 0; j < 32; ++j) { pin2(whh1[j]); pin2(wih2[j]); pin2(whh2[j]); }

    v2f wih1p = (v2f){w_ih1[rowA], w_ih1[rowB]};
    v2f b1p   = (v2f){b_ih1[rowA] + b_hh1[rowA], b_ih1[rowB] + b_hh1[rowB]};
    v2f b2p   = (v2f){b_ih2[rowA] + b_hh2[rowA], b_ih2[rowB] + b_hh2[rowB]};
    pin2(wih1p); pin2(b1p); pin2(b2p);
    float wfck = (h && k < HID) ? w_fc[k] : 0.0f;
    pinf(wfck);
    const float bfc = b_fc[0];

    // y-component activation constants: h0 -> tanh (g), h1 -> sigmoid (o)
    const float cy = h ? (-L2E) : (-2.0f * L2E);
    const float my = h ? 1.0f : 2.0f;
    const float ay = h ? 0.0f : -1.0f;

    float c1 = 0.0f, c2 = 0.0f, xv = 0.0f;
    const float* xp   = x   + (size_t)b * TSTEPS;
    float*       outp = out + (size_t)b * TSTEPS;
    const v4f*   h2v  = (const v4f*)h2buf;

    for (int t = 0; t <= TSTEPS; ++t) {
        // h1(t-1) lives at parity (t-1)&1; h1(t) goes to parity t&1
        const v4f* h1rd = (const v4f*)(h1buf + ((t & 1) ? 0 : 64));
        float*     h1wr = h1buf + ((t & 1) ? 64 : 0);

        // Read h1(t-1) ONCE (feeds both W_hh1 and W_ih2 matvecs) + h2(t-2).
        v4f H1c[8], H2c[8];
#pragma unroll
        for (int c = 0; c < 8; ++c) { H1c[c] = h1rd[c]; H2c[c] = h2v[c]; }

        if (t < TSTEPS) {
            // ================= layer 1, step t =================
            if ((t & 63) == 0) xv = xp[t + lane];     // coalesced 64-step chunk
            const float xt = __int_as_float(
                __builtin_amdgcn_readlane(__float_as_int(xv), t & 63));
            v2f a0 = (v2f){fmaf(xt, wih1p.x, b1p.x), fmaf(xt, wih1p.y, b1p.y)};
            v2f a1 = (v2f){0.0f, 0.0f};
            v2f a2 = (v2f){0.0f, 0.0f};
            v2f a3 = (v2f){0.0f, 0.0f};
#pragma unroll
            for (int c = 0; c < 8; ++c) {
                v2f lo = H1c[c].xy;
                v2f hi = H1c[c].zw;
                pk_fma_lo(a0, whh1[4 * c + 0], lo);
                pk_fma_hi(a1, whh1[4 * c + 1], lo);
                pk_fma_lo(a2, whh1[4 * c + 2], hi);
                pk_fma_hi(a3, whh1[4 * c + 3], hi);
            }
            v2f pre = (a0 + a1) + (a2 + a3);
            float gx = frcp(1.0f + fexp2(pre.x * (-L2E)));           // i (h0) / f (h1)
            float gy = fmaf(frcp(1.0f + fexp2(pre.y * cy)), my, ay); // g (h0) / o (h1)
            float p  = gx * gy;                                      // h0: i*g
            float px = __shfl_xor(p, 32);
            c1 = fmaf(gx, c1, px);                                   // h1: f*c1 + i*g
            float tc = fmaf(2.0f, frcp(1.0f + fexp2(c1 * (-2.0f * L2E))), -1.0f);
            float hh = gy * tc;                                      // h1: o*tanh(c1)
            h1wr[wr_off] = hh;
        }

        if (t > 0) {
            // ================= layer 2, step t-1 =================
            v2f b0 = b2p;
            v2f b1 = (v2f){0.0f, 0.0f};
            v2f b2 = (v2f){0.0f, 0.0f};
            v2f b3 = (v2f){0.0f, 0.0f};
            v2f d0 = (v2f){0.0f, 0.0f};
            v2f d1 = (v2f){0.0f, 0.0f};
            v2f d2 = (v2f){0.0f, 0.0f};
            v2f d3 = (v2f){0.0f, 0.0f};
#pragma unroll
            for (int c = 0; c < 8; ++c) {
                v2f ulo = H1c[c].xy;                  // h1(t-1), reused from top read
                v2f uhi = H1c[c].zw;
                v2f vlo = H2c[c].xy;                  // h2(t-2)
                v2f vhi = H2c[c].zw;
                pk_fma_lo(b0, wih2[4 * c + 0], ulo);
                pk_fma_lo(d0, whh2[4 * c + 0], vlo);
                pk_fma_hi(b1, wih2[4 * c + 1], ulo);
                pk_fma_hi(d1, whh2[4 * c + 1], vlo);
                pk_fma_lo(b2, wih2[4 * c + 2], uhi);
                pk_fma_lo(d2, whh2[4 * c + 2], vhi);
                pk_fma_hi(b3, wih2[4 * c + 3], uhi);
                pk_fma_hi(d3, whh2[4 * c + 3], vhi);
            }
            v2f pre = ((b0 + b1) + (b2 + b3)) + ((d0 + d1) + (d2 + d3));
            float gx = frcp(1.0f + fexp2(pre.x * (-L2E)));
            float gy = fmaf(frcp(1.0f + fexp2(pre.y * cy)), my, ay);
            float p  = gx * gy;
            float px = __shfl_xor(p, 32);
            c2 = fmaf(gx, c2, px);
            float tc = fmaf(2.0f, frcp(1.0f + fexp2(c2 * (-2.0f * L2E))), -1.0f);
            float hh = gy * tc;                                      // h2(t-1)
            h2buf[wr_off] = hh;
            // fc head on the VALU pipe (DPP); store from lane 63
            float s = dpp_reduce63(wfck * hh);
            if (lane == 63) outp[t - 1] = s + bfc;
        }
    }
}

extern "C" void kernel_launch(void* const* d_in, const int* in_sizes, int n_in,
                              void* d_out, int out_size, void* d_ws, size_t ws_size,
                              hipStream_t stream)
{
    const float* x     = (const float*)d_in[0];
    const float* w_ih1 = (const float*)d_in[1];
    const float* w_hh1 = (const float*)d_in[2];
    const float* b_ih1 = (const float*)d_in[3];
    const float* b_hh1 = (const float*)d_in[4];
    const float* w_ih2 = (const float*)d_in[5];
    const float* w_hh2 = (const float*)d_in[6];
    const float* b_ih2 = (const float*)d_in[7];
    const float* b_hh2 = (const float*)d_in[8];
    const float* w_fc  = (const float*)d_in[9];
    const float* b_fc  = (const float*)d_in[10];
    float* out = (float*)d_out;

    lstm2_kernel<<<BATCH, 64, 0, stream>>>(x, w_ih1, w_hh1, b_ih1, b_hh1,
                                           w_ih2, w_hh2, b_ih2, b_hh2,
                                           w_fc, b_fc, out);
}

// Round 4
// 1013.709 us; speedup vs baseline: 1.9213x; 1.3530x over previous
//
#include <hip/hip_runtime.h>

typedef float v2f __attribute__((ext_vector_type(2)));
typedef float v4f __attribute__((ext_vector_type(4)));

#define HID 30
#define TSTEPS 2048
#define BATCH 512
#define L2E 1.4426950408889634f

// acc(pair) += w(pair) * broadcast(src1.lo)  — VOP3P needs PAIR operands.
__device__ __forceinline__ void pk_fma_lo(v2f& acc, v2f w, v2f hp) {
    asm("v_pk_fma_f32 %0, %1, %2, %0 op_sel:[0,0,0] op_sel_hi:[1,0,1]"
        : "+v"(acc) : "v"(w), "v"(hp));
}
// acc(pair) += w(pair) * broadcast(src1.hi)
__device__ __forceinline__ void pk_fma_hi(v2f& acc, v2f w, v2f hp) {
    asm("v_pk_fma_f32 %0, %1, %2, %0 op_sel:[0,1,0] op_sel_hi:[1,1,1]"
        : "+v"(acc) : "v"(w), "v"(hp));
}
// Opaque barrier: forbids rematerializing weight loads inside the t-loop.
__device__ __forceinline__ void pin2(v2f& v) { asm("" : "+v"(v)); }
__device__ __forceinline__ void pinf(float& v) { asm("" : "+v"(v)); }

__device__ __forceinline__ float fexp2(float x) { return __builtin_amdgcn_exp2f(x); }
__device__ __forceinline__ float frcp(float x)  { return __builtin_amdgcn_rcpf(x); }

// Wave-wide sum via DPP (VALU pipe; off the recurrence path). Valid in lane 63.
__device__ __forceinline__ float dpp_reduce63(float x) {
    x += __int_as_float(__builtin_amdgcn_update_dpp(0, __float_as_int(x), 0x111, 0xf, 0xf, true));
    x += __int_as_float(__builtin_amdgcn_update_dpp(0, __float_as_int(x), 0x112, 0xf, 0xf, true));
    x += __int_as_float(__builtin_amdgcn_update_dpp(0, __float_as_int(x), 0x114, 0xf, 0xf, true));
    x += __int_as_float(__builtin_amdgcn_update_dpp(0, __float_as_int(x), 0x118, 0xf, 0xf, true));
    x += __int_as_float(__builtin_amdgcn_update_dpp(0, __float_as_int(x), 0x142, 0xf, 0xf, true));
    x += __int_as_float(__builtin_amdgcn_update_dpp(0, __float_as_int(x), 0x143, 0xf, 0xf, true));
    return x;
}

// Block-per-batch 2-wave pipelined LSTM.
// wave0 = layer1 (producer of h1), wave1 = layer2 + fc head (consumer).
// One __syncthreads per timestep; h1 parity-double-buffered in LDS.
// Within each wave: lane = (k = lane&31, h = lane>>5); gates {i,g} on h=0, {f,o} on h=1
// -> a single cross-half shuffle (the i*g product) per step.
__global__ __launch_bounds__(128, 1)
void lstm2_kernel(const float* __restrict__ x,
                  const float* __restrict__ w_ih1, const float* __restrict__ w_hh1,
                  const float* __restrict__ b_ih1, const float* __restrict__ b_hh1,
                  const float* __restrict__ w_ih2, const float* __restrict__ w_hh2,
                  const float* __restrict__ b_ih2, const float* __restrict__ b_hh2,
                  const float* __restrict__ w_fc,  const float* __restrict__ b_fc,
                  float* __restrict__ out)
{
    const int b    = blockIdx.x;
    const int tid  = threadIdx.x;
    const int wave = tid >> 6;            // 0 = layer1, 1 = layer2
    const int lane = tid & 63;
    const int k    = lane & 31;
    const int h    = lane >> 5;
    const int kk   = (k < HID) ? k : (HID - 1);   // lanes k=30,31 duplicate unit 29
    const int rowA = h * 30 + kk;         // h0: i-row,  h1: f-row
    const int rowB = 60 + h * 30 + kk;    // h0: g-row,  h1: o-row
    // h=1 writes the real h at [kk]; h=0 dumps its duplicate at [kk+32]
    const int wr_off = kk + (h ? 0 : 32);

    __shared__ __align__(16) float h1buf[2][64];  // h1(t) lives in h1buf[t&1]
    __shared__ __align__(16) float h2buf[64];     // wave1-private recurrence state
    ((float*)h1buf)[tid] = 0.0f;
    if (tid < 64) h2buf[tid] = 0.0f;
    __syncthreads();

    // ---- per-wave loop-invariant packed (rowA,rowB) weights in VGPRs ----
    v2f wA[32], wB[32];                   // wave0: {whh1, unused}; wave1: {wih2, whh2}
    v2f wih1p = (v2f){0.0f, 0.0f};
    v2f bp    = (v2f){0.0f, 0.0f};
    float wfck = 0.0f;
    if (wave == 0) {
#pragma unroll
        for (int j = 0; j < 32; ++j) {
            wA[j] = (j < HID) ? (v2f){w_hh1[rowA * HID + j], w_hh1[rowB * HID + j]}
                              : (v2f){0.0f, 0.0f};
            wB[j] = (v2f){0.0f, 0.0f};
        }
        wih1p = (v2f){w_ih1[rowA], w_ih1[rowB]};
        bp    = (v2f){b_ih1[rowA] + b_hh1[rowA], b_ih1[rowB] + b_hh1[rowB]};
    } else {
#pragma unroll
        for (int j = 0; j < 32; ++j) {
            wA[j] = (j < HID) ? (v2f){w_ih2[rowA * HID + j], w_ih2[rowB * HID + j]}
                              : (v2f){0.0f, 0.0f};
            wB[j] = (j < HID) ? (v2f){w_hh2[rowA * HID + j], w_hh2[rowB * HID + j]}
                              : (v2f){0.0f, 0.0f};
        }
        bp   = (v2f){b_ih2[rowA] + b_hh2[rowA], b_ih2[rowB] + b_hh2[rowB]};
        wfck = (h && k < HID) ? w_fc[k] : 0.0f;
    }
#pragma unroll
    for (int j = 0; j < 32; ++j) { pin2(wA[j]); pin2(wB[j]); }
    pin2(wih1p); pin2(bp); pinf(wfck);
    const float bfc = b_fc[0];

    // y-component activation constants: h0 -> tanh (g), h1 -> sigmoid (o)
    const float cy = h ? (-L2E) : (-2.0f * L2E);
    const float my = h ? 1.0f : 2.0f;
    const float ay = h ? 0.0f : -1.0f;

    float cst = 0.0f;                     // c1 (wave0) / c2 (wave1)
    float xv  = 0.0f;
    const float* xp   = x   + (size_t)b * TSTEPS;
    float*       outp = out + (size_t)b * TSTEPS;

    for (int tt = 0; tt <= TSTEPS; ++tt) {
        __syncthreads();                  // h1(tt-1) handoff + WAR protection
        // both waves read h1(tt-1) from parity (tt-1)&1 == 1-(tt&1)
        const v4f* rd1 = (const v4f*)h1buf[1 - (tt & 1)];

        if (wave == 0) {
            if (tt < TSTEPS) {
                // ---------------- layer 1, step tt ----------------
                if ((tt & 63) == 0) xv = xp[tt + lane];   // coalesced 64-step chunk
                const float xt = __int_as_float(
                    __builtin_amdgcn_readlane(__float_as_int(xv), tt & 63));
                v2f a0 = (v2f){fmaf(xt, wih1p.x, bp.x), fmaf(xt, wih1p.y, bp.y)};
                v2f a1 = (v2f){0.0f, 0.0f};
                v2f a2 = (v2f){0.0f, 0.0f};
                v2f a3 = (v2f){0.0f, 0.0f};
#pragma unroll
                for (int c = 0; c < 8; ++c) {
                    v4f hc = rd1[c];                      // uniform-address broadcast
                    v2f lo = hc.xy, hi = hc.zw;
                    pk_fma_lo(a0, wA[4 * c + 0], lo);
                    pk_fma_hi(a1, wA[4 * c + 1], lo);
                    pk_fma_lo(a2, wA[4 * c + 2], hi);
                    pk_fma_hi(a3, wA[4 * c + 3], hi);
                }
                v2f pre = (a0 + a1) + (a2 + a3);
                float gx = frcp(1.0f + fexp2(pre.x * (-L2E)));           // i / f
                float gy = fmaf(frcp(1.0f + fexp2(pre.y * cy)), my, ay); // g / o
                float p  = gx * gy;
                float px = __shfl_xor(p, 32);
                cst = fmaf(gx, cst, px);                                 // c1
                float tc = fmaf(2.0f, frcp(1.0f + fexp2(cst * (-2.0f * L2E))), -1.0f);
                h1buf[tt & 1][wr_off] = gy * tc;                         // h1(tt)
            }
        } else {
            if (tt > 0) {
                // ---------------- layer 2, step tt-1 ----------------
                const v4f* rd2 = (const v4f*)h2buf;       // h2(tt-2), own-wave RAW safe
                v2f b0 = bp;
                v2f b1 = (v2f){0.0f, 0.0f};
                v2f b2 = (v2f){0.0f, 0.0f};
                v2f b3 = (v2f){0.0f, 0.0f};
                v2f d0 = (v2f){0.0f, 0.0f};
                v2f d1 = (v2f){0.0f, 0.0f};
                v2f d2 = (v2f){0.0f, 0.0f};
                v2f d3 = (v2f){0.0f, 0.0f};
#pragma unroll
                for (int c = 0; c < 8; ++c) {
                    v4f u = rd1[c];                       // h1(tt-1)
                    v4f v = rd2[c];                       // h2(tt-2)
                    v2f ulo = u.xy, uhi = u.zw;
                    v2f vlo = v.xy, vhi = v.zw;
                    pk_fma_lo(b0, wA[4 * c + 0], ulo);
                    pk_fma_lo(d0, wB[4 * c + 0], vlo);
                    pk_fma_hi(b1, wA[4 * c + 1], ulo);
                    pk_fma_hi(d1, wB[4 * c + 1], vlo);
                    pk_fma_lo(b2, wA[4 * c + 2], uhi);
                    pk_fma_lo(d2, wB[4 * c + 2], vhi);
                    pk_fma_hi(b3, wA[4 * c + 3], uhi);
                    pk_fma_hi(d3, wB[4 * c + 3], vhi);
                }
                v2f pre = ((b0 + b1) + (b2 + b3)) + ((d0 + d1) + (d2 + d3));
                float gx = frcp(1.0f + fexp2(pre.x * (-L2E)));
                float gy = fmaf(frcp(1.0f + fexp2(pre.y * cy)), my, ay);
                float p  = gx * gy;
                float px = __shfl_xor(p, 32);
                cst = fmaf(gx, cst, px);                                 // c2
                float tc = fmaf(2.0f, frcp(1.0f + fexp2(cst * (-2.0f * L2E))), -1.0f);
                float hh = gy * tc;                                      // h2(tt-1)
                h2buf[wr_off] = hh;
                // fc head (off the recurrence path)
                float s = dpp_reduce63(wfck * hh);
                if (lane == 63) outp[tt - 1] = s + bfc;
            }
        }
    }
}

extern "C" void kernel_launch(void* const* d_in, const int* in_sizes, int n_in,
                              void* d_out, int out_size, void* d_ws, size_t ws_size,
                              hipStream_t stream)
{
    const float* x     = (const float*)d_in[0];
    const float* w_ih1 = (const float*)d_in[1];
    const float* w_hh1 = (const float*)d_in[2];
    const float* b_ih1 = (const float*)d_in[3];
    const float* b_hh1 = (const float*)d_in[4];
    const float* w_ih2 = (const float*)d_in[5];
    const float* w_hh2 = (const float*)d_in[6];
    const float* b_ih2 = (const float*)d_in[7];
    const float* b_hh2 = (const float*)d_in[8];
    const float* w_fc  = (const float*)d_in[9];
    const float* b_fc  = (const float*)d_in[10];
    float* out = (float*)d_out;

    lstm2_kernel<<<BATCH, 128, 0, stream>>>(x, w_ih1, w_hh1, b_ih1, b_hh1,
                                            w_ih2, w_hh2, b_ih2, b_hh2,
                                            w_fc, b_fc, out);
}